// Round 6
// baseline (268.543 us; speedup 1.0000x reference)
//
#include <hip/hip_runtime.h>
#include <math.h>

#define L_DIM   8192
#define NCH     64
#define M_TOT_F 262144.0f
#define EPS_F   1e-5f
#define NBLK    512
#define TPB     256
#define GTPB    8     // gram tiles per block: 512*8 = 4096
#define ATPB    8     // apply tiles per block

typedef float f32x4 __attribute__((ext_vector_type(4)));
typedef short bf16x8 __attribute__((ext_vector_type(8)));

union U8 { unsigned u[4]; bf16x8 v; };

// ---- LDS arena (79376 B, phase-aliased; 2 blocks/CU: 158752 <= 163840) ----
#define OFF_A      0
#define OFF_T1H    0
#define OFF_T1L    9216
#define OFF_T2H    18432
#define OFF_G1     0
#define OFF_G2P    16384
#define OFF_PH     33024
#define OFF_PL     42240
#define OFF_SH     51456   // after NS: wmh (8192 B) + bias (256 B @ +8192)
#define OFF_SL     60672   // after NS: wml
#define OFF_T2L    69888
#define OFF_MU     79104
#define OFF_SCAL   79360
#define SM_BYTES   79376

// ---- software grid barrier state (zero-init at module load; self-resetting) ----
__device__ unsigned swb_cnt[8 * 32];   // 8 group counters, 128 B apart
__device__ unsigned swb_root;
__device__ unsigned swb_gen;

__device__ __forceinline__ void grid_barrier(int bid) {
    __syncthreads();                       // all block work done, vm/lgkm drained
    if (threadIdx.x == 0) {
        __threadfence();                   // prior global writes visible device-wide
        unsigned mygen = __hip_atomic_load(&swb_gen, __ATOMIC_ACQUIRE, __HIP_MEMORY_SCOPE_AGENT);
        int g = bid & 7;
        unsigned o = __hip_atomic_fetch_add(&swb_cnt[g * 32], 1u, __ATOMIC_ACQ_REL, __HIP_MEMORY_SCOPE_AGENT);
        if (o == (NBLK / 8 - 1)) {         // last of this group
            unsigned r = __hip_atomic_fetch_add(&swb_root, 1u, __ATOMIC_ACQ_REL, __HIP_MEMORY_SCOPE_AGENT);
            if (r == 7) {                  // last group: reset, then release everyone
#pragma unroll
                for (int i = 0; i < 8; ++i)
                    __hip_atomic_store(&swb_cnt[i * 32], 0u, __ATOMIC_RELAXED, __HIP_MEMORY_SCOPE_AGENT);
                __hip_atomic_store(&swb_root, 0u, __ATOMIC_RELAXED, __HIP_MEMORY_SCOPE_AGENT);
                __hip_atomic_fetch_add(&swb_gen, 1u, __ATOMIC_RELEASE, __HIP_MEMORY_SCOPE_AGENT);
            }
        }
        while (__hip_atomic_load(&swb_gen, __ATOMIC_ACQUIRE, __HIP_MEMORY_SCOPE_AGENT) == mygen)
            __builtin_amdgcn_s_sleep(2);
        __threadfence();
    }
    __syncthreads();
}

__device__ __forceinline__ void cvt2(float f0, float f1, unsigned& h, unsigned& l) {
    unsigned u0 = __float_as_uint(f0), u1 = __float_as_uint(f1);
    h = (u0 >> 16) | (u1 & 0xFFFF0000u);
    float r0 = f0 - __uint_as_float(u0 & 0xFFFF0000u);
    float r1 = f1 - __uint_as_float(u1 & 0xFFFF0000u);
    l = (__float_as_uint(r0) >> 16) | (__float_as_uint(r1) & 0xFFFF0000u);
}

__device__ __forceinline__ void split16(float v, unsigned short& h, unsigned short& l) {
    unsigned u = __float_as_uint(v);
    h = (unsigned short)(u >> 16);
    float r = v - __uint_as_float(u & 0xFFFF0000u);
    l = (unsigned short)(__float_as_uint(r) >> 16);
}

__device__ __forceinline__ float b2f(unsigned short h) {
    return __uint_as_float(((unsigned)h) << 16);
}

__device__ __forceinline__ float aload(const float* p) {
    return __hip_atomic_load(p, __ATOMIC_RELAXED, __HIP_MEMORY_SCOPE_AGENT);
}

__device__ __forceinline__ f32x4 mfma16(bf16x8 a, bf16x8 b, f32x4 c) {
    return __builtin_amdgcn_mfma_f32_16x16x32_bf16(a, b, c, 0, 0, 0);
}

__device__ __forceinline__ f32x4 fzero() {
    f32x4 z; z[0] = 0.f; z[1] = 0.f; z[2] = 0.f; z[3] = 0.f; return z;
}

// 64x64 symmetric matmul on hi/lo bf16 plane pairs (stride 72 shorts)
__device__ __forceinline__ void mm_core(f32x4* acc,
                                        const unsigned short* Xh, const unsigned short* Xl,
                                        const unsigned short* Yh, const unsigned short* Yl,
                                        int w, int m, int q) {
#pragma unroll
    for (int k0 = 0; k0 < 64; k0 += 32) {
        bf16x8 xh = *(const bf16x8*)&Xh[(16 * w + m) * 72 + k0 + 8 * q];
        bf16x8 xl = *(const bf16x8*)&Xl[(16 * w + m) * 72 + k0 + 8 * q];
#pragma unroll
        for (int nb = 0; nb < 4; ++nb) {
            bf16x8 yh = *(const bf16x8*)&Yh[(16 * nb + m) * 72 + k0 + 8 * q];
            bf16x8 yl = *(const bf16x8*)&Yl[(16 * nb + m) * 72 + k0 + 8 * q];
            acc[nb] = mfma16(xh, yh, acc[nb]);
            acc[nb] = mfma16(xh, yl, acc[nb]);
            acc[nb] = mfma16(xl, yh, acc[nb]);
        }
    }
}

__device__ __forceinline__ void mm_pl(unsigned short* Dh, unsigned short* Dl,
                                      const unsigned short* Xh, const unsigned short* Xl,
                                      const unsigned short* Yh, const unsigned short* Yl,
                                      int w, int m, int q) {
    f32x4 acc[4];
#pragma unroll
    for (int nb = 0; nb < 4; ++nb) acc[nb] = fzero();
    mm_core(acc, Xh, Xl, Yh, Yl, w, m, q);
#pragma unroll
    for (int nb = 0; nb < 4; ++nb)
#pragma unroll
        for (int r = 0; r < 4; ++r) {
            int row = 16 * w + 4 * q + r, col = 16 * nb + m;
            unsigned short h, l;
            split16(acc[nb][r], h, l);
            Dh[row * 72 + col] = h;
            Dl[row * 72 + col] = l;
        }
}

__global__ __launch_bounds__(TPB, 2) void mega_kernel(const float* __restrict__ X,
                                                      float* __restrict__ Y,
                                                      float* __restrict__ ws) {
    __shared__ __align__(16) unsigned char smem[SM_BYTES];

    const int bid  = blockIdx.x;
    const int tid  = threadIdx.x;
    const int w    = tid >> 6;
    const int lane = tid & 63;
    const int m    = lane & 15;
    const int q    = lane >> 4;
    const int cp   = tid & 31;
    const int lg   = tid >> 5;

    unsigned short* hfrag = (unsigned short*)(smem + OFF_A);          // [2][4096] shorts
    unsigned short* lfrag = (unsigned short*)(smem + OFF_A + 16384);  // [2][4096] shorts

    // ===== phase Z: block-sliced zeroing of ws (agent-scope atomic stores) =====
    if (tid < 17) {
        int g = bid * 17 + tid;
        if (g < 8256)
            __hip_atomic_store(&ws[g], 0.0f, __ATOMIC_RELAXED, __HIP_MEMORY_SCOPE_AGENT);
    }

    // ===== phase G: gram accumulators (registers; no ws access yet) =====
    f32x4 acc1[4], acc2[4];
#pragma unroll
    for (int nb = 0; nb < 4; ++nb) { acc1[nb] = fzero(); acc2[nb] = fzero(); }
    float sacc = 0.f;
    {
        const int row = 16 * w + m;
        const int tile0 = bid * GTPB;
        float4 v[4];
        {
            int t0 = tile0;
            const float* src = X + ((size_t)((t0 >> 7) * NCH + row)) * L_DIM + ((t0 & 127) << 6) + 8 * q;
            v[0] = *(const float4*)(src);
            v[1] = *(const float4*)(src + 4);
            v[2] = *(const float4*)(src + 32);
            v[3] = *(const float4*)(src + 36);
        }

        for (int t = 0; t < GTPB; ++t) {
            const int p = t & 1;
#pragma unroll
            for (int i = 0; i < 4; ++i) sacc += v[i].x + v[i].y + v[i].z + v[i].w;

            bf16x8 Ah[2], Al[2];
#pragma unroll
            for (int k = 0; k < 2; ++k) {
                U8 H, L;
                cvt2(v[2 * k].x,     v[2 * k].y,     H.u[0], L.u[0]);
                cvt2(v[2 * k].z,     v[2 * k].w,     H.u[1], L.u[1]);
                cvt2(v[2 * k + 1].x, v[2 * k + 1].y, H.u[2], L.u[2]);
                cvt2(v[2 * k + 1].z, v[2 * k + 1].w, H.u[3], L.u[3]);
                Ah[k] = H.v; Al[k] = L.v;
                int chunk = ((w * 2 + k) * 4 + q) * 16 + m;
                *(bf16x8*)&hfrag[p * 4096 + chunk * 8] = H.v;
                *(bf16x8*)&lfrag[p * 4096 + chunk * 8] = L.v;
            }

            if (t + 1 < GTPB) {
                int tn = tile0 + t + 1;
                const float* src = X + ((size_t)((tn >> 7) * NCH + row)) * L_DIM + ((tn & 127) << 6) + 8 * q;
                v[0] = *(const float4*)(src);
                v[1] = *(const float4*)(src + 4);
                v[2] = *(const float4*)(src + 32);
                v[3] = *(const float4*)(src + 36);
            }
            __syncthreads();

#pragma unroll
            for (int k = 0; k < 2; ++k)
#pragma unroll
                for (int nb = 0; nb < 4; ++nb) {
                    int chunk = ((nb * 2 + k) * 4 + q) * 16 + m;
                    bf16x8 bh = *(const bf16x8*)&hfrag[p * 4096 + chunk * 8];
                    bf16x8 bl = *(const bf16x8*)&lfrag[p * 4096 + chunk * 8];
                    acc1[nb] = mfma16(Ah[k], bh, acc1[nb]);
                    acc2[nb] = mfma16(Ah[k], bl, acc2[nb]);
                }
        }
    }

    grid_barrier(bid);   // zeroing complete everywhere; safe to accumulate

    // ===== accumulate gram into ws via device-scope atomicAdd (R4-proven) =====
    {
        const int row = 16 * w + m;
#pragma unroll
        for (int nb = 0; nb < 4; ++nb)
#pragma unroll
            for (int r = 0; r < 4; ++r) {
                int grow = 16 * w + 4 * q + r;
                int gcol = 16 * nb + m;
                atomicAdd(&ws[grow * 64 + gcol],        acc1[nb][r]);
                atomicAdd(&ws[4096 + grow * 64 + gcol], acc2[nb][r]);
            }
        sacc += __shfl_xor(sacc, 16);
        sacc += __shfl_xor(sacc, 32);
        if (q == 0) atomicAdd(&ws[8192 + row], sacc);
    }

    // hoist first apply tile's global loads (latency hidden under barrier + NS)
    float4 va[2], vb[2];
    {
        int tile = bid * ATPB;
        const float* xb = X + (size_t)(tile >> 7) * (NCH * L_DIM) + ((tile & 127) << 6)
                          + (size_t)(2 * cp) * L_DIM + 4 * lg;
#pragma unroll
        for (int ss = 0; ss < 2; ++ss) {
            va[ss] = *(const float4*)(xb + 32 * ss);
            vb[ss] = *(const float4*)(xb + 32 * ss + L_DIM);
        }
    }

    grid_barrier(bid);   // all atomicAdds complete; ws final

    // ===== phase N: per-block redundant Newton-Schulz =====
    unsigned short* Ph  = (unsigned short*)(smem + OFF_PH);
    unsigned short* Pl  = (unsigned short*)(smem + OFF_PL);
    unsigned short* Sh  = (unsigned short*)(smem + OFF_SH);
    unsigned short* Sl  = (unsigned short*)(smem + OFF_SL);
    unsigned short* T1h = (unsigned short*)(smem + OFF_T1H);
    unsigned short* T1l = (unsigned short*)(smem + OFF_T1L);
    unsigned short* T2h = (unsigned short*)(smem + OFF_T2H);
    unsigned short* T2l = (unsigned short*)(smem + OFF_T2L);
    float* mu   = (float*)(smem + OFF_MU);
    float* scal = (float*)(smem + OFF_SCAL);
    unsigned short* wmh = (unsigned short*)(smem + OFF_SH);           // overwrites Sh
    unsigned short* wml = (unsigned short*)(smem + OFF_SL);           // overwrites Sl
    float* bias = (float*)(smem + OFF_SH + 8192);
    float* G1f  = (float*)(smem + OFF_G1);    // [4096]
    float* G2p  = (float*)(smem + OFF_G2P);   // [64*65] padded
    const float inv_m = 1.0f / M_TOT_F;

    for (int e = tid; e < 4096; e += 256) {
        int i = e >> 6, j = e & 63;
        G1f[e]          = aload(&ws[e]);
        G2p[i * 65 + j] = aload(&ws[4096 + e]);
    }
    if (tid < 64) mu[tid] = aload(&ws[8192 + tid]) * inv_m;
    __syncthreads();

    if (tid < 64) {
        float g  = (G1f[tid * 65] + 2.0f * G2p[tid * 66]) * inv_m;
        float sd = g - mu[tid] * mu[tid] + EPS_F;
#pragma unroll
        for (int off = 32; off >= 1; off >>= 1) sd += __shfl_xor(sd, off);
        if (tid == 0) { scal[0] = 1.0f / sd; scal[1] = sqrtf(1.0f / sd); }
    }
    __syncthreads();
    const float rTr = scal[0];

    for (int e = tid; e < 4096; e += 256) {
        int i = e >> 6, j = e & 63;
        float g   = (G1f[e] + G2p[i * 65 + j] + G2p[j * 65 + i]) * inv_m;
        float sig = g - mu[i] * mu[j] + ((i == j) ? EPS_F : 0.f);
        float sn  = sig * rTr;
        unsigned short h, l;
        split16(sn, h, l);
        Sh[i * 72 + j] = h; Sl[i * 72 + j] = l;
        float pv = ((i == j) ? 1.5f : 0.f) - 0.5f * sn;   // closed-form NS iter 1
        split16(pv, h, l);
        Ph[i * 72 + j] = h; Pl[i * 72 + j] = l;
    }
    __syncthreads();

    for (int it = 0; it < 4; ++it) {
        mm_pl(T1h, T1l, Ph, Pl, Ph, Pl, w, m, q);    // T1 = P^2  (clobbers G1f/G2p - dead)
        __syncthreads();
        mm_pl(T2h, T2l, T1h, T1l, Ph, Pl, w, m, q);  // T2 = P^3
        __syncthreads();
        f32x4 acc[4];
#pragma unroll
        for (int nb = 0; nb < 4; ++nb) acc[nb] = fzero();
        mm_core(acc, T2h, T2l, Sh, Sl, w, m, q);     // U = P^3 * S_N
#pragma unroll
        for (int nb = 0; nb < 4; ++nb)
#pragma unroll
            for (int r = 0; r < 4; ++r) {
                int row = 16 * w + 4 * q + r, col = 16 * nb + m;
                int pidx = row * 72 + col;
                float pold = b2f(Ph[pidx]) + b2f(Pl[pidx]);
                float pv = 1.5f * pold - 0.5f * acc[nb][r];
                unsigned short h, l;
                split16(pv, h, l);
                Ph[pidx] = h; Pl[pidx] = l;
            }
        __syncthreads();
    }

    const float s = scal[1];
    if (tid < 64) {
        float a = 0.f;
#pragma unroll 8
        for (int k = 0; k < 64; ++k)
            a += (b2f(Ph[tid * 72 + k]) + b2f(Pl[tid * 72 + k])) * mu[k];
        bias[tid] = -a * s;
    }
    for (int e = tid; e < 4096; e += 256) {
        int i = e >> 6, j = e & 63;
        float v = (b2f(Ph[i * 72 + j]) + b2f(Pl[i * 72 + j])) * s;
        unsigned short h, l;
        split16(v, h, l);
        wmh[e] = h;    // row-major [c][k] stride 64 — A-fragment order for apply
        wml[e] = l;
    }
    __syncthreads();

    // ===== phase A: Y = wm @ x + bias =====
    bf16x8 Ah2[2], Al2[2];
#pragma unroll
    for (int kk = 0; kk < 2; ++kk) {
        Ah2[kk] = *(const bf16x8*)&wmh[(16 * w + m) * 64 + 32 * kk + 8 * q];
        Al2[kk] = *(const bf16x8*)&wml[(16 * w + m) * 64 + 32 * kk + 8 * q];
    }
    const float4 bias4 = *(const float4*)&bias[16 * w + 4 * q];

    for (int t = 0; t < ATPB; ++t) {
        int tile = bid * ATPB + t;
        int bidx = tile >> 7;
        int l0   = (tile & 127) << 6;
        const int p = t & 1;
        unsigned* hw2 = (unsigned*)(hfrag + p * 4096);
        unsigned* lw2 = (unsigned*)(lfrag + p * 4096);

#pragma unroll
        for (int ss = 0; ss < 2; ++ss) {
            float fa[4], fb[4];
            *(float4*)fa = va[ss];
            *(float4*)fb = vb[ss];
#pragma unroll
            for (int i = 0; i < 4; ++i) {
                int l = 4 * lg + 32 * ss + i;
                unsigned h, lo2;
                cvt2(fa[i], fb[i], h, lo2);
                int widx = l * 32 + (((cp >> 2) ^ (l & 7)) << 2) + (cp & 3);
                hw2[widx] = h;
                lw2[widx] = lo2;
            }
        }

        if (t + 1 < ATPB) {
            int tn = tile + 1;
            const float* xb = X + (size_t)(tn >> 7) * (NCH * L_DIM) + ((tn & 127) << 6)
                              + (size_t)(2 * cp) * L_DIM + 4 * lg;
#pragma unroll
            for (int ss = 0; ss < 2; ++ss) {
                va[ss] = *(const float4*)(xb + 32 * ss);
                vb[ss] = *(const float4*)(xb + 32 * ss + L_DIM);
            }
        }
        __syncthreads();

        f32x4 acc[4];
#pragma unroll
        for (int nb = 0; nb < 4; ++nb) {
            acc[nb][0] = bias4.x; acc[nb][1] = bias4.y;
            acc[nb][2] = bias4.z; acc[nb][3] = bias4.w;
        }
#pragma unroll
        for (int kk = 0; kk < 2; ++kk)
#pragma unroll
            for (int nb = 0; nb < 4; ++nb) {
                int l = 16 * nb + m;
                int saddr = l * 64 + ((((4 * kk + q) ^ (l & 7))) << 3);
                bf16x8 bh = *(const bf16x8*)&hfrag[p * 4096 + saddr];
                bf16x8 bl = *(const bf16x8*)&lfrag[p * 4096 + saddr];
                acc[nb] = mfma16(Ah2[kk], bh, acc[nb]);
                acc[nb] = mfma16(Ah2[kk], bl, acc[nb]);
                acc[nb] = mfma16(Al2[kk], bh, acc[nb]);
            }

#pragma unroll
        for (int nb = 0; nb < 4; ++nb)
#pragma unroll
            for (int rr = 0; rr < 4; ++rr)
                Y[((size_t)bidx * NCH + 16 * w + 4 * q + rr) * L_DIM + l0 + 16 * nb + m] = acc[nb][rr];
    }
}

extern "C" void kernel_launch(void* const* d_in, const int* in_sizes, int n_in,
                              void* d_out, int out_size, void* d_ws, size_t ws_size,
                              hipStream_t stream) {
    const float* X = (const float*)d_in[0];
    float* Y  = (float*)d_out;
    float* ws = (float*)d_ws;
    hipLaunchKernelGGL(mega_kernel, dim3(NBLK), dim3(TPB), 0, stream, X, Y, ws);
}

// Round 7
// 153.821 us; speedup vs baseline: 1.7458x; 1.7458x over previous
//
#include <hip/hip_runtime.h>
#include <math.h>

#define L_DIM   8192
#define NCH     64
#define M_TOT_F 262144.0f
#define EPS_F   1e-5f
#define GTPB    4     // gram tiles per block: 1024*4 = 4096
#define ATPB    4     // apply tiles per block: 1024*4 = 4096

typedef float f32x4 __attribute__((ext_vector_type(4)));
typedef short bf16x8 __attribute__((ext_vector_type(8)));

union U8 { unsigned u[4]; bf16x8 v; };

// split two fp32 into packed bf16 hi (truncated) and bf16 lo (residual)
__device__ __forceinline__ void cvt2(float f0, float f1, unsigned& h, unsigned& l) {
    unsigned u0 = __float_as_uint(f0), u1 = __float_as_uint(f1);
    h = (u0 >> 16) | (u1 & 0xFFFF0000u);
    float r0 = f0 - __uint_as_float(u0 & 0xFFFF0000u);
    float r1 = f1 - __uint_as_float(u1 & 0xFFFF0000u);
    l = (__float_as_uint(r0) >> 16) | (__float_as_uint(r1) & 0xFFFF0000u);
}

__device__ __forceinline__ void split16(float v, unsigned short& h, unsigned short& l) {
    unsigned u = __float_as_uint(v);
    h = (unsigned short)(u >> 16);
    float r = v - __uint_as_float(u & 0xFFFF0000u);
    l = (unsigned short)(__float_as_uint(r) >> 16);
}

__device__ __forceinline__ f32x4 mfma16(bf16x8 a, bf16x8 b, f32x4 c) {
    return __builtin_amdgcn_mfma_f32_16x16x32_bf16(a, b, c, 0, 0, 0);
}

__device__ __forceinline__ f32x4 fzero() {
    f32x4 z; z[0] = 0.f; z[1] = 0.f; z[2] = 0.f; z[3] = 0.f; return z;
}

// ---------------- K1: Gram partials — all 4 tiles' loads issued upfront ----------------
__global__ __launch_bounds__(256) void gram_kernel(const float* __restrict__ X,
                                                   float* __restrict__ P) {
    __shared__ __align__(16) unsigned short hfrag[2][4096];
    __shared__ __align__(16) unsigned short lfrag[2][4096];
    const int tid  = threadIdx.x;
    const int w    = tid >> 6;
    const int lane = tid & 63;
    const int m    = lane & 15;
    const int q    = lane >> 4;
    const int row  = 16 * w + m;

    f32x4 acc1[4], acc2[4];
#pragma unroll
    for (int nb = 0; nb < 4; ++nb) { acc1[nb] = fzero(); acc2[nb] = fzero(); }
    float sacc = 0.f;

    const int tile0 = blockIdx.x * GTPB;
    float4 v[GTPB][4];   // all tiles in flight: 16 float4 loads, max MLP
#pragma unroll
    for (int t = 0; t < GTPB; ++t) {
        int tt = tile0 + t;
        const float* src = X + ((size_t)((tt >> 7) * NCH + row)) * L_DIM + ((tt & 127) << 6) + 8 * q;
        v[t][0] = *(const float4*)(src);
        v[t][1] = *(const float4*)(src + 4);
        v[t][2] = *(const float4*)(src + 32);
        v[t][3] = *(const float4*)(src + 36);
    }

#pragma unroll
    for (int t = 0; t < GTPB; ++t) {
        const int p = t & 1;
#pragma unroll
        for (int i = 0; i < 4; ++i) sacc += v[t][i].x + v[t][i].y + v[t][i].z + v[t][i].w;

        bf16x8 Ah[2], Al[2];
#pragma unroll
        for (int k = 0; k < 2; ++k) {
            U8 H, L;
            cvt2(v[t][2 * k].x,     v[t][2 * k].y,     H.u[0], L.u[0]);
            cvt2(v[t][2 * k].z,     v[t][2 * k].w,     H.u[1], L.u[1]);
            cvt2(v[t][2 * k + 1].x, v[t][2 * k + 1].y, H.u[2], L.u[2]);
            cvt2(v[t][2 * k + 1].z, v[t][2 * k + 1].w, H.u[3], L.u[3]);
            Ah[k] = H.v; Al[k] = L.v;
            int chunk = ((w * 2 + k) * 4 + q) * 16 + m;
            *(bf16x8*)&hfrag[p][chunk * 8] = H.v;
            *(bf16x8*)&lfrag[p][chunk * 8] = L.v;
        }
        __syncthreads();

#pragma unroll
        for (int k = 0; k < 2; ++k)
#pragma unroll
            for (int nb = 0; nb < 4; ++nb) {
                int chunk = ((nb * 2 + k) * 4 + q) * 16 + m;
                bf16x8 bh = *(const bf16x8*)&hfrag[p][chunk * 8];
                bf16x8 bl = *(const bf16x8*)&lfrag[p][chunk * 8];
                acc1[nb] = mfma16(Ah[k], bh, acc1[nb]);
                acc2[nb] = mfma16(Ah[k], bl, acc2[nb]);
            }
    }

    float* base = P + (size_t)blockIdx.x * 8256;
#pragma unroll
    for (int nb = 0; nb < 4; ++nb)
#pragma unroll
        for (int r = 0; r < 4; ++r) {
            int grow = 16 * w + 4 * q + r;
            int gcol = 16 * nb + m;
            base[grow * 64 + gcol]        = acc1[nb][r];
            base[4096 + grow * 64 + gcol] = acc2[nb][r];
        }
    sacc += __shfl_xor(sacc, 16);
    sacc += __shfl_xor(sacc, 32);
    if (q == 0) base[8192 + row] = sacc;
}

// ---------------- K1b: reduce 1024 partials -> ws[0..8256)  (32 loads in flight) -------
__global__ __launch_bounds__(256) void reduce_kernel(const float* __restrict__ P,
                                                     float* __restrict__ ws) {
    const int tid = threadIdx.x;
    const int w = tid >> 6, lane = tid & 63;
    const int e0 = blockIdx.x * 64;
    float a0 = 0.f, a1 = 0.f, a2 = 0.f, a3 = 0.f;
#pragma unroll 8
    for (int i = 0; i < 64; ++i) {
        const float* p = P + (size_t)(w * 256 + 4 * i) * 8256 + e0 + lane;
        a0 += p[0];
        a1 += p[8256];
        a2 += p[2 * 8256];
        a3 += p[3 * 8256];
    }
    float a = (a0 + a1) + (a2 + a3);
    __shared__ float red[4][64];
    red[w][lane] = a;
    __syncthreads();
    if (w == 0)
        ws[e0 + lane] = red[0][lane] + red[1][lane] + red[2][lane] + red[3][lane];
}

// ---------------- K2: Newton-Schulz — 512 threads, 8-wave split per matmul -----------
// wave w8: rows 16*(w8>>1)..+15, column blocks nb in {2*(w8&1), 2*(w8&1)+1}
__device__ __forceinline__ void mm_core8(f32x4* acc,
                                         const unsigned short* Xh, const unsigned short* Xl,
                                         const unsigned short* Yh, const unsigned short* Yl,
                                         int rg, int nbb, int m, int q) {
#pragma unroll
    for (int k0 = 0; k0 < 64; k0 += 32) {
        bf16x8 xh = *(const bf16x8*)&Xh[(16 * rg + m) * 72 + k0 + 8 * q];
        bf16x8 xl = *(const bf16x8*)&Xl[(16 * rg + m) * 72 + k0 + 8 * q];
#pragma unroll
        for (int j = 0; j < 2; ++j) {
            int nb = nbb + j;
            bf16x8 yh = *(const bf16x8*)&Yh[(16 * nb + m) * 72 + k0 + 8 * q];
            bf16x8 yl = *(const bf16x8*)&Yl[(16 * nb + m) * 72 + k0 + 8 * q];
            acc[j] = mfma16(xh, yh, acc[j]);
            acc[j] = mfma16(xh, yl, acc[j]);
            acc[j] = mfma16(xl, yh, acc[j]);
        }
    }
}

__device__ __forceinline__ void mm_pl8(unsigned short* Dh, unsigned short* Dl,
                                       const unsigned short* Xh, const unsigned short* Xl,
                                       const unsigned short* Yh, const unsigned short* Yl,
                                       int rg, int nbb, int m, int q) {
    f32x4 acc[2];
    acc[0] = fzero(); acc[1] = fzero();
    mm_core8(acc, Xh, Xl, Yh, Yl, rg, nbb, m, q);
#pragma unroll
    for (int j = 0; j < 2; ++j)
#pragma unroll
        for (int r = 0; r < 4; ++r) {
            int row = 16 * rg + 4 * q + r, col = 16 * (nbb + j) + m;
            unsigned short h, l;
            split16(acc[j][r], h, l);
            Dh[row * 72 + col] = h;
            Dl[row * 72 + col] = l;
        }
}

__global__ __launch_bounds__(512) void ns_kernel(float* __restrict__ ws) {
    __shared__ __align__(16) float Pf[64 * 68];
    __shared__ __align__(16) unsigned short Ph[64 * 72], Pl[64 * 72];
    __shared__ __align__(16) unsigned short Sh[64 * 72], Sl[64 * 72];
    __shared__ __align__(16) unsigned short T1h[64 * 72], T1l[64 * 72];
    __shared__ __align__(16) unsigned short T2h[64 * 72], T2l[64 * 72];
    __shared__ float mu[64];
    __shared__ float scal[2];

    const int tid = threadIdx.x;
    const int w8 = tid >> 6, lane = tid & 63;
    const int m = lane & 15, q = lane >> 4;
    const int rg = w8 >> 1, nbb = (w8 & 1) << 1;
    const float inv_m = 1.0f / M_TOT_F;

    if (tid < 64) mu[tid] = ws[8192 + tid] * inv_m;
    __syncthreads();

    if (tid < 64) {
        int e = tid * 65;   // diagonal of the 64x64 planes
        float g  = (ws[e] + 2.0f * ws[4096 + e]) * inv_m;
        float sd = g - mu[tid] * mu[tid] + EPS_F;
#pragma unroll
        for (int off = 32; off >= 1; off >>= 1) sd += __shfl_xor(sd, off);
        if (tid == 0) { scal[0] = 1.0f / sd; scal[1] = sqrtf(1.0f / sd); }
    }
    __syncthreads();
    const float rTr = scal[0];

    // S_N planes + closed-form NS iter 1: P1 = 1.5 I - 0.5 S_N
    for (int e = tid; e < 4096; e += 512) {
        int i = e >> 6, j = e & 63;
        float g   = (ws[e] + ws[4096 + e] + ws[4096 + (j << 6) + i]) * inv_m;
        float sig = g - mu[i] * mu[j] + ((i == j) ? EPS_F : 0.f);
        float sn  = sig * rTr;
        unsigned short h, l;
        split16(sn, h, l);
        Sh[i * 72 + j] = h; Sl[i * 72 + j] = l;
        float pv = ((i == j) ? 1.5f : 0.f) - 0.5f * sn;
        Pf[i * 68 + j] = pv;
        split16(pv, h, l);
        Ph[i * 72 + j] = h; Pl[i * 72 + j] = l;
    }
    __syncthreads();

    for (int it = 0; it < 4; ++it) {
        mm_pl8(T1h, T1l, Ph, Pl, Ph, Pl, rg, nbb, m, q);   // T1 = P^2
        __syncthreads();
        mm_pl8(T2h, T2l, T1h, T1l, Ph, Pl, rg, nbb, m, q); // T2 = P^3
        __syncthreads();
        f32x4 acc[2];                                       // U = P^3 * S_N
        acc[0] = fzero(); acc[1] = fzero();
        mm_core8(acc, T2h, T2l, Sh, Sl, rg, nbb, m, q);
#pragma unroll
        for (int j = 0; j < 2; ++j)
#pragma unroll
            for (int r = 0; r < 4; ++r) {
                int row = 16 * rg + 4 * q + r, col = 16 * (nbb + j) + m;
                int idx = row * 68 + col;
                float pv = 1.5f * Pf[idx] - 0.5f * acc[j][r];
                Pf[idx] = pv;
                unsigned short h, l;
                split16(pv, h, l);
                Ph[row * 72 + col] = h;
                Pl[row * 72 + col] = l;
            }
        __syncthreads();
    }

    const float s = scal[1];
    unsigned short* hp = (unsigned short*)ws;
    unsigned short* lp = hp + 4096;
    for (int e = tid; e < 4096; e += 512) {
        int i = e >> 6, j = e & 63;
        float v = Pf[i * 68 + j] * s;
        unsigned short h, l;
        split16(v, h, l);
        hp[e] = h;
        lp[e] = l;
    }
    if (tid < 64) {
        float a = 0.f;
#pragma unroll 8
        for (int k = 0; k < 64; ++k) a += Pf[tid * 68 + k] * mu[k];
        ws[8256 + tid] = -a * s;
    }
}

// ---------------- K3: Y = wm @ x + bias — all 4 tiles' loads issued upfront ----------
__global__ __launch_bounds__(256) void apply_kernel(const float* __restrict__ X,
                                                    float* __restrict__ Y,
                                                    const float* __restrict__ ws) {
    __shared__ __align__(16) unsigned short hplane[2][4096];
    __shared__ __align__(16) unsigned short lplane[2][4096];
    const int tid  = threadIdx.x;
    const int w    = tid >> 6;
    const int lane = tid & 63;
    const int m    = lane & 15;
    const int q    = lane >> 4;
    const int cp   = tid & 31;      // channel pair rows 2cp, 2cp+1
    const int lg   = tid >> 5;      // 0..7

    const unsigned short* hp = (const unsigned short*)ws;
    const unsigned short* lp = hp + 4096;
    bf16x8 Ah[2], Al[2];
#pragma unroll
    for (int kk = 0; kk < 2; ++kk) {
        Ah[kk] = *(const bf16x8*)&hp[(16 * w + m) * 64 + 32 * kk + 8 * q];
        Al[kk] = *(const bf16x8*)&lp[(16 * w + m) * 64 + 32 * kk + 8 * q];
    }
    const float4 bias4 = *(const float4*)&ws[8256 + 16 * w + 4 * q];

    float4 va[ATPB][2], vb[ATPB][2];   // all tiles in flight: 16 float4 loads
#pragma unroll
    for (int t = 0; t < ATPB; ++t) {
        int tile = blockIdx.x * ATPB + t;
        const float* xb = X + (size_t)(tile >> 7) * (NCH * L_DIM) + ((tile & 127) << 6)
                          + (size_t)(2 * cp) * L_DIM + 4 * lg;
#pragma unroll
        for (int ss = 0; ss < 2; ++ss) {
            va[t][ss] = *(const float4*)(xb + 32 * ss);
            vb[t][ss] = *(const float4*)(xb + 32 * ss + L_DIM);
        }
    }

#pragma unroll
    for (int t = 0; t < ATPB; ++t) {
        int tile = blockIdx.x * ATPB + t;
        int bidx = tile >> 7;
        int l0   = (tile & 127) << 6;
        const int p = t & 1;
        unsigned* hw2 = (unsigned*)hplane[p];
        unsigned* lw2 = (unsigned*)lplane[p];

#pragma unroll
        for (int ss = 0; ss < 2; ++ss) {
            float fa[4], fb[4];
            *(float4*)fa = va[t][ss];
            *(float4*)fb = vb[t][ss];
#pragma unroll
            for (int i = 0; i < 4; ++i) {
                int l = 4 * lg + 32 * ss + i;
                unsigned h, lo2;
                cvt2(fa[i], fb[i], h, lo2);
                int widx = l * 32 + (((cp >> 2) ^ (l & 7)) << 2) + (cp & 3);
                hw2[widx] = h;
                lw2[widx] = lo2;
            }
        }
        __syncthreads();

        f32x4 acc[4];
#pragma unroll
        for (int nb = 0; nb < 4; ++nb) {
            acc[nb][0] = bias4.x; acc[nb][1] = bias4.y;
            acc[nb][2] = bias4.z; acc[nb][3] = bias4.w;
        }
#pragma unroll
        for (int kk = 0; kk < 2; ++kk)
#pragma unroll
            for (int nb = 0; nb < 4; ++nb) {
                int l = 16 * nb + m;
                int saddr = l * 64 + ((((4 * kk + q) ^ (l & 7))) << 3);
                bf16x8 bh = *(const bf16x8*)&hplane[p][saddr];
                bf16x8 bl = *(const bf16x8*)&lplane[p][saddr];
                acc[nb] = mfma16(Ah[kk], bh, acc[nb]);
                acc[nb] = mfma16(Ah[kk], bl, acc[nb]);
                acc[nb] = mfma16(Al[kk], bh, acc[nb]);
            }

#pragma unroll
        for (int nb = 0; nb < 4; ++nb)
#pragma unroll
            for (int rr = 0; rr < 4; ++rr)
                Y[((size_t)bidx * NCH + 16 * w + 4 * q + rr) * L_DIM + l0 + 16 * nb + m] = acc[nb][rr];
    }
}

extern "C" void kernel_launch(void* const* d_in, const int* in_sizes, int n_in,
                              void* d_out, int out_size, void* d_ws, size_t ws_size,
                              hipStream_t stream) {
    const float* X = (const float*)d_in[0];
    float* Y  = (float*)d_out;
    float* ws = (float*)d_ws;
    float* scratch = (float*)d_out;   // gram partials live in d_out before apply overwrites it

    hipLaunchKernelGGL(gram_kernel,   dim3(1024), dim3(256), 0, stream, X, scratch);
    hipLaunchKernelGGL(reduce_kernel, dim3(129),  dim3(256), 0, stream, scratch, ws);
    hipLaunchKernelGGL(ns_kernel,     dim3(1),    dim3(512), 0, stream, ws);
    hipLaunchKernelGGL(apply_kernel,  dim3(1024), dim3(256), 0, stream, X, Y, ws);
}